// Round 1
// baseline (393.388 us; speedup 1.0000x reference)
//
#include <hip/hip_runtime.h>

#define L_SEQ 2048
#define BATCH 2
#define CDIM  1024
#define NH    16
#define HD    64

typedef __attribute__((ext_vector_type(8))) short short8;
typedef __attribute__((ext_vector_type(4))) float floatx4;

__device__ __forceinline__ unsigned short f2bf(float f){
  unsigned int u = __builtin_bit_cast(unsigned int, f);
  u += 0x7fffu + ((u >> 16) & 1u);
  return (unsigned short)(u >> 16);
}

__device__ __forceinline__ void gload_lds16(const void* g, void* l){
  typedef __attribute__((address_space(1))) void gv_t;
  typedef __attribute__((address_space(3))) void sv_t;
  __builtin_amdgcn_global_load_lds((gv_t*)(void*)g, (sv_t*)l, 16, 0, 0);
}

// ---------------- prep_x: (L,B,C) f32 -> (B*L, C) bf16 ----------------
__global__ void __launch_bounds__(256) prep_x(const float* __restrict__ x,
                                              unsigned short* __restrict__ xb){
  int idx = blockIdx.x * 256 + threadIdx.x;     // over L*B*C/4 = 1048576
  int c4 = idx & 255;                           // C/4 = 256
  int lb = idx >> 8;                            // l*B + b
  int b  = lb & (BATCH - 1);
  int l  = lb >> 1;
  float4 v = ((const float4*)x)[idx];
  ushort4 s;
  s.x = f2bf(v.x); s.y = f2bf(v.y); s.z = f2bf(v.z); s.w = f2bf(v.w);
  *(ushort4*)&xb[(size_t)(b*L_SEQ + l)*CDIM + c4*4] = s;
}

// ---------------- prep_w: transpose f32 (K,N) -> bf16 (N,K) ----------------
__global__ void __launch_bounds__(256) prep_w(const float* __restrict__ Wq,
    const float* __restrict__ Wk, const float* __restrict__ Wv,
    const float* __restrict__ Wo, unsigned short* __restrict__ Wqkvt,
    unsigned short* __restrict__ Wot){
  __shared__ float tile[32][33];
  int z = blockIdx.z;
  const float* W = (z==0)?Wq:(z==1)?Wk:(z==2)?Wv:Wo;
  unsigned short* dst = (z==3) ? Wot : (Wqkvt + (size_t)z*CDIM*CDIM);
  int tx = threadIdx.x & 31, ty = threadIdx.x >> 5;   // 32 x 8
  int X = blockIdx.x*32, Y = blockIdx.y*32;
  #pragma unroll
  for (int i=0;i<4;i++)
    tile[ty + i*8][tx] = W[(size_t)(Y + ty + i*8)*CDIM + X + tx];
  __syncthreads();
  #pragma unroll
  for (int i=0;i<4;i++)
    dst[(size_t)(X + ty + i*8)*CDIM + Y + tx] = f2bf(tile[tx][ty + i*8]);
}

// ---------------- gemm_bt: C = A(MxK) * Bt(NxK)^T, bf16 MFMA ----------------
// MODE 0: QKV epilogue (bias, scatter to Q/K (B,H,L,hd) and V^T (B,H,hd,L))
// MODE 1: out epilogue (bias bo, fp32 (L,B,C))
template<int MODE>
__global__ void __launch_bounds__(256) gemm_bt(
    const unsigned short* __restrict__ A,
    const unsigned short* __restrict__ Bt,
    int Kdim,
    const float* __restrict__ b0, const float* __restrict__ b1,
    const float* __restrict__ b2,
    unsigned short* __restrict__ qo, unsigned short* __restrict__ ko,
    unsigned short* __restrict__ vo, float* __restrict__ out)
{
  __shared__ unsigned short Asm[128*32];
  __shared__ unsigned short Bsm[128*32];
  const int t    = threadIdx.x;
  const int lane = t & 63;
  const int wave = t >> 6;
  const int wr = wave >> 1, wc = wave & 1;
  const int g = lane >> 4, lr = lane & 15;
  const int rowA0 = blockIdx.x * 128;
  const int rowB0 = blockIdx.y * 128;

  floatx4 acc[4][4] = {};

  const int r_st = t >> 2;          // staging row 0..63
  const int k_st = (t & 3) * 8;     // staging k offset

  for (int k0 = 0; k0 < Kdim; k0 += 32) {
    const unsigned short* ga = A  + (size_t)(rowA0 + r_st) * Kdim + k0 + k_st;
    const unsigned short* gb = Bt + (size_t)(rowB0 + r_st) * Kdim + k0 + k_st;
    gload_lds16(ga,                   &Asm[t*8]);
    gload_lds16(ga + (size_t)64*Kdim, &Asm[2048 + t*8]);
    gload_lds16(gb,                   &Bsm[t*8]);
    gload_lds16(gb + (size_t)64*Kdim, &Bsm[2048 + t*8]);
    __syncthreads();
    short8 af[4], bfr[4];
    #pragma unroll
    for (int mi=0;mi<4;mi++)
      af[mi] = *(const short8*)&Asm[(wr*64 + mi*16 + lr)*32 + g*8];
    #pragma unroll
    for (int ni=0;ni<4;ni++)
      bfr[ni] = *(const short8*)&Bsm[(wc*64 + ni*16 + lr)*32 + g*8];
    #pragma unroll
    for (int mi=0;mi<4;mi++)
      #pragma unroll
      for (int ni=0;ni<4;ni++)
        acc[mi][ni] = __builtin_amdgcn_mfma_f32_16x16x32_bf16(af[mi], bfr[ni], acc[mi][ni], 0, 0, 0);
    __syncthreads();
  }

  #pragma unroll
  for (int mi=0;mi<4;mi++){
    const int rb = rowA0 + wr*64 + mi*16 + g*4;
    #pragma unroll
    for (int ni=0;ni<4;ni++){
      const int col = rowB0 + wc*64 + ni*16 + lr;
      if (MODE == 0) {
        const int sec = col >> 10;
        const int nl  = col & 1023;
        const int h = nl >> 6, d = nl & 63;
        const float* bp = (sec==0) ? b0 : (sec==1) ? b1 : b2;
        const float bias = bp[nl];
        #pragma unroll
        for (int r=0;r<4;r++){
          const int row = rb + r;
          const int b = row >> 11, l = row & 2047;
          const unsigned short hv = f2bf(acc[mi][ni][r] + bias);
          const size_t bh = (size_t)(b*NH + h);
          if (sec == 0)      qo[(bh*L_SEQ + l)*HD + d] = hv;
          else if (sec == 1) ko[(bh*L_SEQ + l)*HD + d] = hv;
          else               vo[(bh*HD + d)*L_SEQ + l] = hv;
        }
      } else {
        const float bias = b0[col];
        #pragma unroll
        for (int r=0;r<4;r++){
          const int row = rb + r;
          const int b = row >> 11, l = row & 2047;
          out[((size_t)l*BATCH + b)*CDIM + col] = acc[mi][ni][r] + bias;
        }
      }
    }
  }
}

// ---------------- flash attention ----------------
__global__ void __launch_bounds__(256) attn_kernel(
    const unsigned short* __restrict__ Qb, const unsigned short* __restrict__ Kb,
    const unsigned short* __restrict__ Vt, const float* __restrict__ rel,
    unsigned short* __restrict__ Ab)
{
  __shared__ float rel_s[2112];
  __shared__ unsigned short Pl[4][16*32];
  const int bh = blockIdx.x;       // b*NH + h, 0..31
  const int qb = blockIdx.y;       // q-block of 64, 0..31
  const int t = threadIdx.x, lane = t & 63, wave = t >> 6;
  const int g = lane >> 4, lr = lane & 15;

  const int base = 2047 - (qb*64 + 63);
  for (int i = t; i < 2112; i += 256) rel_s[i] = rel[base + i];
  __syncthreads();

  const unsigned short* Qp = Qb + (size_t)bh * L_SEQ * HD;
  const unsigned short* Kp = Kb + (size_t)bh * L_SEQ * HD;
  const unsigned short* Vp = Vt + (size_t)bh * HD * L_SEQ;

  const int q0 = qb*64 + wave*16;
  const short8 qf0 = *(const short8*)&Qp[(size_t)(q0 + lr)*HD + g*8];
  const short8 qf1 = *(const short8*)&Qp[(size_t)(q0 + lr)*HD + 32 + g*8];

  floatx4 o[4] = {};
  float m[4], lsum[4];
  #pragma unroll
  for (int r=0;r<4;r++){ m[r] = -1e30f; lsum[r] = 0.f; }
  const int qloc = wave*16 + g*4;
  const float scale = 0.125f;    // hd^-0.5 = 1/8

  for (int kb = 0; kb < L_SEQ; kb += 32) {
    floatx4 s0 = {}, s1 = {};
    short8 kf;
    kf = *(const short8*)&Kp[(size_t)(kb + lr)*HD + g*8];
    s0 = __builtin_amdgcn_mfma_f32_16x16x32_bf16(qf0, kf, s0, 0,0,0);
    kf = *(const short8*)&Kp[(size_t)(kb + lr)*HD + 32 + g*8];
    s0 = __builtin_amdgcn_mfma_f32_16x16x32_bf16(qf1, kf, s0, 0,0,0);
    kf = *(const short8*)&Kp[(size_t)(kb + 16 + lr)*HD + g*8];
    s1 = __builtin_amdgcn_mfma_f32_16x16x32_bf16(qf0, kf, s1, 0,0,0);
    kf = *(const short8*)&Kp[(size_t)(kb + 16 + lr)*HD + 32 + g*8];
    s1 = __builtin_amdgcn_mfma_f32_16x16x32_bf16(qf1, kf, s1, 0,0,0);

    float sv0[4], sv1[4];
    #pragma unroll
    for (int r=0;r<4;r++){
      const int ql = qloc + r;
      sv0[r] = (s0[r] + rel_s[kb + lr - ql + 63]) * scale;
      sv1[r] = (s1[r] + rel_s[kb + 16 + lr - ql + 63]) * scale;
    }
    #pragma unroll
    for (int r=0;r<4;r++){
      float mx = fmaxf(sv0[r], sv1[r]);
      mx = fmaxf(mx, __shfl_xor(mx, 1, 64));
      mx = fmaxf(mx, __shfl_xor(mx, 2, 64));
      mx = fmaxf(mx, __shfl_xor(mx, 4, 64));
      mx = fmaxf(mx, __shfl_xor(mx, 8, 64));
      const float mn = fmaxf(m[r], mx);
      const float al = __expf(m[r] - mn);
      m[r] = mn;
      const float p0 = __expf(sv0[r] - mn);
      const float p1 = __expf(sv1[r] - mn);
      sv0[r] = p0; sv1[r] = p1;
      float ss = p0 + p1;
      ss += __shfl_xor(ss, 1, 64);
      ss += __shfl_xor(ss, 2, 64);
      ss += __shfl_xor(ss, 4, 64);
      ss += __shfl_xor(ss, 8, 64);
      lsum[r] = lsum[r]*al + ss;
      o[0][r]*=al; o[1][r]*=al; o[2][r]*=al; o[3][r]*=al;
    }
    unsigned short* pw = &Pl[wave][0];
    #pragma unroll
    for (int r=0;r<4;r++){
      pw[(g*4+r)*32 + lr]      = f2bf(sv0[r]);
      pw[(g*4+r)*32 + 16 + lr] = f2bf(sv1[r]);
    }
    const short8 pf = *(const short8*)&pw[lr*32 + g*8];
    #pragma unroll
    for (int fb=0; fb<4; fb++){
      const short8 vf = *(const short8*)&Vp[(size_t)(fb*16 + lr)*L_SEQ + kb + g*8];
      o[fb] = __builtin_amdgcn_mfma_f32_16x16x32_bf16(pf, vf, o[fb], 0,0,0);
    }
  }
  const int b = bh >> 4, h = bh & 15;
  #pragma unroll
  for (int fb=0; fb<4; fb++){
    #pragma unroll
    for (int r=0;r<4;r++){
      const int qq = q0 + g*4 + r;
      const float val = o[fb][r] / lsum[r];
      Ab[((size_t)(b*L_SEQ + qq))*CDIM + h*HD + fb*16 + lr] = f2bf(val);
    }
  }
}

extern "C" void kernel_launch(void* const* d_in, const int* in_sizes, int n_in,
                              void* d_out, int out_size, void* d_ws, size_t ws_size,
                              hipStream_t stream) {
  const float* x   = (const float*)d_in[0];
  const float* Wq  = (const float*)d_in[1];
  const float* bq  = (const float*)d_in[2];
  const float* Wk  = (const float*)d_in[3];
  const float* bk  = (const float*)d_in[4];
  const float* Wv  = (const float*)d_in[5];
  const float* bv  = (const float*)d_in[6];
  const float* Wo  = (const float*)d_in[7];
  const float* bo  = (const float*)d_in[8];
  const float* rel = (const float*)d_in[9];
  float* out = (float*)d_out;

  char* ws = (char*)d_ws;
  unsigned short* Xb    = (unsigned short*)(ws);                    // 8 MB (aliased with Ab)
  unsigned short* Wqkvt = (unsigned short*)(ws + (8u  << 20));      // 6 MB
  unsigned short* Wot   = (unsigned short*)(ws + (14u << 20));      // 2 MB
  unsigned short* Qb    = (unsigned short*)(ws + (16u << 20));      // 8 MB
  unsigned short* Kb    = (unsigned short*)(ws + (24u << 20));      // 8 MB
  unsigned short* Vt    = (unsigned short*)(ws + (32u << 20));      // 8 MB
  unsigned short* Ab    = Xb;  // Xb dead after QKV GEMM

  prep_x<<<4096, 256, 0, stream>>>(x, Xb);
  prep_w<<<dim3(32,32,4), 256, 0, stream>>>(Wq, Wk, Wv, Wo, Wqkvt, Wot);
  gemm_bt<0><<<dim3(32,24), 256, 0, stream>>>(Xb, Wqkvt, CDIM, bq, bk, bv,
                                              Qb, Kb, Vt, nullptr);
  attn_kernel<<<dim3(32,32), 256, 0, stream>>>(Qb, Kb, Vt, rel, Ab);
  gemm_bt<1><<<dim3(32,8), 256, 0, stream>>>(Ab, Wot, CDIM, bo, nullptr, nullptr,
                                             nullptr, nullptr, nullptr, out);
}

// Round 3
// 392.931 us; speedup vs baseline: 1.0012x; 1.0012x over previous
//
#include <hip/hip_runtime.h>

#define L_SEQ 2048
#define BATCH 2
#define CDIM  1024
#define NH    16
#define HD    64

typedef __attribute__((ext_vector_type(8))) short short8;
typedef __attribute__((ext_vector_type(4))) float floatx4;

__device__ __forceinline__ unsigned short f2bf(float f){
  unsigned int u = __builtin_bit_cast(unsigned int, f);
  u += 0x7fffu + ((u >> 16) & 1u);
  return (unsigned short)(u >> 16);
}

__device__ __forceinline__ void gload_lds16(const void* g, void* l){
  typedef __attribute__((address_space(1))) void gv_t;
  typedef __attribute__((address_space(3))) void sv_t;
  __builtin_amdgcn_global_load_lds((gv_t*)(void*)g, (sv_t*)l, 16, 0, 0);
}

// ---------------- prep_x: (L,B,C) f32 -> (B*L, C) bf16 ----------------
__global__ void __launch_bounds__(256) prep_x(const float* __restrict__ x,
                                              unsigned short* __restrict__ xb){
  int idx = blockIdx.x * 256 + threadIdx.x;     // over L*B*C/4 = 1048576
  int c4 = idx & 255;                           // C/4 = 256
  int lb = idx >> 8;                            // l*B + b
  int b  = lb & (BATCH - 1);
  int l  = lb >> 1;
  float4 v = ((const float4*)x)[idx];
  ushort4 s;
  s.x = f2bf(v.x); s.y = f2bf(v.y); s.z = f2bf(v.z); s.w = f2bf(v.w);
  *(ushort4*)&xb[(size_t)(b*L_SEQ + l)*CDIM + c4*4] = s;
}

// ---------------- prep_w: transpose f32 (K,N) -> bf16 (N,K) ----------------
__global__ void __launch_bounds__(256) prep_w(const float* __restrict__ Wq,
    const float* __restrict__ Wk, const float* __restrict__ Wv,
    const float* __restrict__ Wo, unsigned short* __restrict__ Wqkvt,
    unsigned short* __restrict__ Wot){
  __shared__ float tile[32][33];
  int z = blockIdx.z;
  const float* W = (z==0)?Wq:(z==1)?Wk:(z==2)?Wv:Wo;
  unsigned short* dst = (z==3) ? Wot : (Wqkvt + (size_t)z*CDIM*CDIM);
  int tx = threadIdx.x & 31, ty = threadIdx.x >> 5;   // 32 x 8
  int X = blockIdx.x*32, Y = blockIdx.y*32;
  #pragma unroll
  for (int i=0;i<4;i++)
    tile[ty + i*8][tx] = W[(size_t)(Y + ty + i*8)*CDIM + X + tx];
  __syncthreads();
  #pragma unroll
  for (int i=0;i<4;i++)
    dst[(size_t)(X + ty + i*8)*CDIM + Y + tx] = f2bf(tile[tx][ty + i*8]);
}

// ---------------- gemm_bt: C = A(MxK) * Bt(NxK)^T, bf16 MFMA ----------------
// MODE 0: QKV epilogue (bias, scatter; Q pre-scaled by hd^-0.5)
// MODE 1: out epilogue (bias bo, fp32 (L,B,C))
template<int MODE>
__global__ void __launch_bounds__(256) gemm_bt(
    const unsigned short* __restrict__ A,
    const unsigned short* __restrict__ Bt,
    int Kdim,
    const float* __restrict__ b0, const float* __restrict__ b1,
    const float* __restrict__ b2,
    unsigned short* __restrict__ qo, unsigned short* __restrict__ ko,
    unsigned short* __restrict__ vo, float* __restrict__ out)
{
  __shared__ unsigned short Asm[128*32];
  __shared__ unsigned short Bsm[128*32];
  const int t    = threadIdx.x;
  const int lane = t & 63;
  const int wave = t >> 6;
  const int wr = wave >> 1, wc = wave & 1;
  const int g = lane >> 4, lr = lane & 15;
  const int rowA0 = blockIdx.x * 128;
  const int rowB0 = blockIdx.y * 128;

  floatx4 acc[4][4] = {};

  const int r_st = t >> 2;          // staging row 0..63
  const int k_st = (t & 3) * 8;     // staging k offset

  for (int k0 = 0; k0 < Kdim; k0 += 32) {
    const unsigned short* ga = A  + (size_t)(rowA0 + r_st) * Kdim + k0 + k_st;
    const unsigned short* gb = Bt + (size_t)(rowB0 + r_st) * Kdim + k0 + k_st;
    gload_lds16(ga,                   &Asm[t*8]);
    gload_lds16(ga + (size_t)64*Kdim, &Asm[2048 + t*8]);
    gload_lds16(gb,                   &Bsm[t*8]);
    gload_lds16(gb + (size_t)64*Kdim, &Bsm[2048 + t*8]);
    __syncthreads();
    short8 af[4], bfr[4];
    #pragma unroll
    for (int mi=0;mi<4;mi++)
      af[mi] = *(const short8*)&Asm[(wr*64 + mi*16 + lr)*32 + g*8];
    #pragma unroll
    for (int ni=0;ni<4;ni++)
      bfr[ni] = *(const short8*)&Bsm[(wc*64 + ni*16 + lr)*32 + g*8];
    #pragma unroll
    for (int mi=0;mi<4;mi++)
      #pragma unroll
      for (int ni=0;ni<4;ni++)
        acc[mi][ni] = __builtin_amdgcn_mfma_f32_16x16x32_bf16(af[mi], bfr[ni], acc[mi][ni], 0, 0, 0);
    __syncthreads();
  }

  #pragma unroll
  for (int mi=0;mi<4;mi++){
    const int rb = rowA0 + wr*64 + mi*16 + g*4;
    #pragma unroll
    for (int ni=0;ni<4;ni++){
      const int col = rowB0 + wc*64 + ni*16 + lr;
      if (MODE == 0) {
        const int sec = col >> 10;
        const int nl  = col & 1023;
        const int h = nl >> 6, d = nl & 63;
        const float* bp = (sec==0) ? b0 : (sec==1) ? b1 : b2;
        const float bias = bp[nl];
        #pragma unroll
        for (int r=0;r<4;r++){
          const int row = rb + r;
          const int b = row >> 11, l = row & 2047;
          float v = acc[mi][ni][r] + bias;
          if (sec == 0) v *= 0.125f;             // fold hd^-0.5 into Q
          const unsigned short hv = f2bf(v);
          const size_t bh = (size_t)(b*NH + h);
          if (sec == 0)      qo[(bh*L_SEQ + l)*HD + d] = hv;
          else if (sec == 1) ko[(bh*L_SEQ + l)*HD + d] = hv;
          else               vo[(bh*HD + d)*L_SEQ + l] = hv;
        }
      } else {
        const float bias = b0[col];
        #pragma unroll
        for (int r=0;r<4;r++){
          const int row = rb + r;
          const int b = row >> 11, l = row & 2047;
          out[((size_t)l*BATCH + b)*CDIM + col] = acc[mi][ni][r] + bias;
        }
      }
    }
  }
}

// ---------------- flash attention (swapped-QK^T, lane-local rows) ----------------
// grid: x = q-block (32), y = b*NH+h (32). Consecutive blocks share K/V in L2.
__global__ void __launch_bounds__(256) attn_kernel(
    const unsigned short* __restrict__ Qb, const unsigned short* __restrict__ Kb,
    const unsigned short* __restrict__ Vt, const float* __restrict__ rel,
    unsigned short* __restrict__ Ab)
{
  __shared__ float rel_s[2112];
  __shared__ unsigned int Pl[4][16*20];   // [q=16][20 u32], stride 20 -> 2-way max
  const int qb = blockIdx.x;
  const int bh = blockIdx.y;
  const int t = threadIdx.x, lane = t & 63, wave = t >> 6;
  const int g = lane >> 4, lr = lane & 15;

  // rel, pre-scaled; used index range is [0, 2110]
  const int base = 2047 - (qb*64 + 63);
  for (int i = t; i < 2111; i += 256) rel_s[i] = rel[base + i] * 0.125f;
  __syncthreads();

  const unsigned short* Qp = Qb + (size_t)bh * L_SEQ * HD;
  const unsigned short* Kp = Kb + (size_t)bh * L_SEQ * HD;
  const unsigned short* Vp = Vt + (size_t)bh * HD * L_SEQ;

  const int q0 = qb*64 + wave*16;                 // this wave's q-rows
  const short8 qf0 = *(const short8*)&Qp[(size_t)(q0 + lr)*HD + g*8];
  const short8 qf1 = *(const short8*)&Qp[(size_t)(q0 + lr)*HD + 32 + g*8];

  floatx4 o[4] = {};
  float m = -1e30f, lsum = 0.f;
  // rel idx = kb + relb + r (+16 for upper half); q = q0 + lr
  const int relb = 63 + g*4 - (wave*16 + lr);

  unsigned int* pw = &Pl[wave][0];

  for (int kb = 0; kb < L_SEQ; kb += 32) {
    // S^T = K·Q^T : lane holds keys {kb+g*4+r, kb+16+g*4+r} for q-row q0+lr
    floatx4 s0 = {}, s1 = {};
    short8 kf;
    kf = *(const short8*)&Kp[(size_t)(kb + lr)*HD + g*8];
    s0 = __builtin_amdgcn_mfma_f32_16x16x32_bf16(kf, qf0, s0, 0,0,0);
    kf = *(const short8*)&Kp[(size_t)(kb + lr)*HD + 32 + g*8];
    s0 = __builtin_amdgcn_mfma_f32_16x16x32_bf16(kf, qf1, s0, 0,0,0);
    kf = *(const short8*)&Kp[(size_t)(kb + 16 + lr)*HD + g*8];
    s1 = __builtin_amdgcn_mfma_f32_16x16x32_bf16(kf, qf0, s1, 0,0,0);
    kf = *(const short8*)&Kp[(size_t)(kb + 16 + lr)*HD + 32 + g*8];
    s1 = __builtin_amdgcn_mfma_f32_16x16x32_bf16(kf, qf1, s1, 0,0,0);

    float p[8];
    #pragma unroll
    for (int r=0;r<4;r++){
      p[r]     = s0[r] + rel_s[kb + relb + r];
      p[4 + r] = s1[r] + rel_s[kb + relb + r + 16];
    }
    // row-max: 7 in-register fmax + 2 shfl (reduce over g)
    float mx = fmaxf(fmaxf(fmaxf(p[0],p[1]),fmaxf(p[2],p[3])),
                     fmaxf(fmaxf(p[4],p[5]),fmaxf(p[6],p[7])));
    mx = fmaxf(mx, __shfl_xor(mx, 16, 64));
    mx = fmaxf(mx, __shfl_xor(mx, 32, 64));
    const float mn = fmaxf(m, mx);
    const float al = __expf(m - mn);
    m = mn;
    #pragma unroll
    for (int i=0;i<8;i++) p[i] = __expf(p[i] - mn);
    float ss = ((p[0]+p[1])+(p[2]+p[3])) + ((p[4]+p[5])+(p[6]+p[7]));
    ss += __shfl_xor(ss, 16, 64);
    ss += __shfl_xor(ss, 32, 64);
    lsum = lsum*al + ss;
    #pragma unroll
    for (int fb=0; fb<4; fb++)
      #pragma unroll
      for (int r=0;r<4;r++) o[fb][r] *= al;

    // P -> LDS [q=lr][key], packed bf16 pairs; then read B-fragment
    pw[lr*20 + 2*g    ] = (unsigned)f2bf(p[0]) | ((unsigned)f2bf(p[1])<<16);
    pw[lr*20 + 2*g + 1] = (unsigned)f2bf(p[2]) | ((unsigned)f2bf(p[3])<<16);
    pw[lr*20 + 8 + 2*g    ] = (unsigned)f2bf(p[4]) | ((unsigned)f2bf(p[5])<<16);
    pw[lr*20 + 8 + 2*g + 1] = (unsigned)f2bf(p[6]) | ((unsigned)f2bf(p[7])<<16);
    asm volatile("" ::: "memory");    // order ds_write before ds_read (in-order LDS pipe)
    const short8 pf = *(const short8*)&pw[lr*20 + 4*g];
    asm volatile("" ::: "memory");    // order read before next iter's writes
    #pragma unroll
    for (int fb=0; fb<4; fb++){
      const short8 vf = *(const short8*)&Vp[(size_t)(fb*16 + lr)*L_SEQ + kb + g*8];
      o[fb] = __builtin_amdgcn_mfma_f32_16x16x32_bf16(vf, pf, o[fb], 0,0,0);
    }
  }

  // lane (g,lr) holds attn[q=q0+lr][d = fb*16 + g*4 + r]
  const float inv = 1.f / lsum;
  const int b = bh >> 4, h = bh & 15;
  unsigned short* outp = &Ab[((size_t)(b*L_SEQ + q0 + lr))*CDIM + h*HD];
  #pragma unroll
  for (int fb=0; fb<4; fb++){
    #pragma unroll
    for (int rp=0; rp<2; rp++){
      const float v0 = o[fb][2*rp]   * inv;
      const float v1 = o[fb][2*rp+1] * inv;
      *(unsigned int*)&outp[fb*16 + g*4 + 2*rp] =
          (unsigned)f2bf(v0) | ((unsigned)f2bf(v1) << 16);
    }
  }
}

extern "C" void kernel_launch(void* const* d_in, const int* in_sizes, int n_in,
                              void* d_out, int out_size, void* d_ws, size_t ws_size,
                              hipStream_t stream) {
  const float* x   = (const float*)d_in[0];
  const float* Wq  = (const float*)d_in[1];
  const float* bq  = (const float*)d_in[2];
  const float* Wk  = (const float*)d_in[3];
  const float* bk  = (const float*)d_in[4];
  const float* Wv  = (const float*)d_in[5];
  const float* bv  = (const float*)d_in[6];
  const float* Wo  = (const float*)d_in[7];
  const float* bo  = (const float*)d_in[8];
  const float* rel = (const float*)d_in[9];
  float* out = (float*)d_out;

  char* ws = (char*)d_ws;
  unsigned short* Xb    = (unsigned short*)(ws);                    // 8 MB (aliased with Ab)
  unsigned short* Wqkvt = (unsigned short*)(ws + (8u  << 20));      // 6 MB
  unsigned short* Wot   = (unsigned short*)(ws + (14u << 20));      // 2 MB
  unsigned short* Qb    = (unsigned short*)(ws + (16u << 20));      // 8 MB
  unsigned short* Kb    = (unsigned short*)(ws + (24u << 20));      // 8 MB
  unsigned short* Vt    = (unsigned short*)(ws + (32u << 20));      // 8 MB
  unsigned short* Ab    = Xb;  // Xb dead after QKV GEMM

  prep_x<<<4096, 256, 0, stream>>>(x, Xb);
  prep_w<<<dim3(32,32,4), 256, 0, stream>>>(Wq, Wk, Wv, Wo, Wqkvt, Wot);
  gemm_bt<0><<<dim3(32,24), 256, 0, stream>>>(Xb, Wqkvt, CDIM, bq, bk, bv,
                                              Qb, Kb, Vt, nullptr);
  attn_kernel<<<dim3(32,32), 256, 0, stream>>>(Qb, Kb, Vt, rel, Ab);
  gemm_bt<1><<<dim3(32,8), 256, 0, stream>>>(Ab, Wot, CDIM, bo, nullptr, nullptr,
                                             nullptr, nullptr, nullptr, out);
}